// Round 2
// baseline (221.361 us; speedup 1.0000x reference)
//
#include <hip/hip_runtime.h>
#include <math.h>

#define Bc 4
#define Vc 4
#define Hc 256
#define Wc 384
#define HWc (Hc*Wc)               // 98304
#define TOTc (Bc*Vc*HWc)          // 1572864
#define SCALE_MIN_c 1e-05f
#define SCALE_MAX_c 30.0f
#define EPS_c 1e-08f

// Output section offsets (in floats)
#define MEANS_OFF  ((size_t)0)
#define SCALES_OFF ((size_t)TOTc*3)
#define ROT_OFF    ((size_t)TOTc*6)
#define HARM_OFF   ((size_t)TOTc*10)
#define OPAC_OFF   ((size_t)TOTc*13)

// 4 pixels per thread, zero LDS, zero barriers.
// Each thread: 14 independent VMEM loads issued up front (12x dwordx4 raw,
// 1x f4 depth, 1x f4 opac), per-view constants computed once (amortized x4),
// all stores are float4. Math is op-for-op identical to the previous kernel.
__global__ __launch_bounds__(256, 4) void ga_kernel(
    const float* __restrict__ ext,    // (B,V,4,4)
    const float* __restrict__ intr,   // (B,V,3,3)
    const float* __restrict__ depths, // (B,V,H,W)
    const float* __restrict__ opac,   // (B,V,H,W)
    const float* __restrict__ raw,    // (B,V,H,W,12)
    float* __restrict__ out)
{
    const int tid = threadIdx.x;
    const int T   = blockIdx.x * 256 + tid;      // global thread id; pixels 4T..4T+3
    const int bview   = blockIdx.x / 96;         // HWc/1024 = 96 blocks per view
    const int pixBase = (blockIdx.x - bview * 96) * 1024 + (tid << 2);

    // ---- issue ALL loads up front: 14 VMEM ops in flight per thread ----
    const float4* rb = reinterpret_cast<const float4*>(raw) + (size_t)T * 12;
    const float4 v0 = rb[0],  v1 = rb[1],  v2  = rb[2];    // pixel 0
    const float4 v3 = rb[3],  v4 = rb[4],  v5  = rb[5];    // pixel 1
    const float4 v6 = rb[6],  v7 = rb[7],  v8  = rb[8];    // pixel 2
    const float4 v9 = rb[9],  v10 = rb[10], v11 = rb[11];  // pixel 3
    const float4 d4 = reinterpret_cast<const float4*>(depths)[T];
    const float4 o4 = reinterpret_cast<const float4*>(opac)[T];

    // ---- per-view constants (uniform s_loads; computed once per thread) ----
    const float* E = ext  + bview * 16;
    const float* I = intr + bview * 9;

    // Rc2w = Rw2c^T
    const float R0 = E[0], R1 = E[4], R2 = E[8];
    const float R3 = E[1], R4 = E[5], R5 = E[9];
    const float R6 = E[2], R7 = E[6], R8 = E[10];
    const float t0 = E[3], t1 = E[7], t2 = E[11];
    const float O0 = -(R0*t0 + R1*t1 + R2*t2);
    const float O1 = -(R3*t0 + R4*t1 + R5*t2);
    const float O2 = -(R6*t0 + R7*t1 + R8*t2);

    const float a00 = I[0]*(1.0f/Wc), a01 = I[1]*(1.0f/Wc), a02 = I[2]*(1.0f/Wc);
    const float a10 = I[3]*(1.0f/Hc), a11 = I[4]*(1.0f/Hc), a12 = I[5]*(1.0f/Hc);
    const float a20 = I[6],           a21 = I[7],           a22 = I[8];
    const float det = a00*(a11*a22 - a12*a21)
                    - a01*(a10*a22 - a12*a20)
                    + a02*(a10*a21 - a11*a20);
    const float id = 1.0f / det;
    const float K0 = (a11*a22 - a12*a21)*id;
    const float K1 = (a02*a21 - a01*a22)*id;
    const float K2 = (a01*a12 - a02*a11)*id;
    const float K3 = (a12*a20 - a10*a22)*id;
    const float K4 = (a00*a22 - a02*a20)*id;
    const float K5 = (a02*a10 - a00*a12)*id;
    const float K6 = (a10*a21 - a11*a20)*id;
    const float K7 = (a01*a20 - a00*a21)*id;
    const float K8 = (a00*a11 - a01*a10)*id;

    const float det2 = a00*a11 - a01*a10;
    const float mult = 0.1f * ((a11*(1.0f/Wc) - a01*(1.0f/Hc))
                             + (-a10*(1.0f/Wc) + a00*(1.0f/Hc))) / det2;

    // c2w quaternion from Rc2w (branchless argmax, identical to prev kernel)
    const float qa0 = sqrtf(fmaxf(0.0f, 1.0f + R0 + R4 + R8));
    const float qa1 = sqrtf(fmaxf(0.0f, 1.0f + R0 - R4 - R8));
    const float qa2 = sqrtf(fmaxf(0.0f, 1.0f - R0 + R4 - R8));
    const float qa3 = sqrtf(fmaxf(0.0f, 1.0f - R0 - R4 + R8));
    float bq = qa0;
    float b0 = qa0*qa0, b1 = R7 - R5, b2 = R2 - R6, b3 = R3 - R1;
    {
        const bool s1 = qa1 > bq;
        b0 = s1 ? (R7 - R5)   : b0;
        b1 = s1 ? (qa1*qa1)   : b1;
        b2 = s1 ? (R3 + R1)   : b2;
        b3 = s1 ? (R2 + R6)   : b3;
        bq = s1 ? qa1 : bq;
        const bool s2 = qa2 > bq;
        b0 = s2 ? (R2 - R6)   : b0;
        b1 = s2 ? (R3 + R1)   : b1;
        b2 = s2 ? (qa2*qa2)   : b2;
        b3 = s2 ? (R5 + R7)   : b3;
        bq = s2 ? qa2 : bq;
        const bool s3 = qa3 > bq;
        b0 = s3 ? (R3 - R1)   : b0;
        b1 = s3 ? (R6 + R2)   : b1;
        b2 = s3 ? (R7 + R5)   : b2;
        b3 = s3 ? (qa3*qa3)   : b3;
        bq = s3 ? qa3 : bq;
    }
    const float dd = 1.0f / (2.0f * fmaxf(bq, 0.1f));
    const float q0 = b0*dd, q1 = b1*dd, q2 = b2*dd, q3 = b3*dd;
    const float qn = 1.0f / sqrtf(q0*q0 + q1*q1 + q2*q2 + q3*q3);
    const float aw = q0*qn, ax = q1*qn, ay = q2*qn, az = q3*qn;

    // opacity passthrough (fully coalesced float4)
    reinterpret_cast<float4*>(out + OPAC_OFF)[T] = o4;

    // ---- per-pixel geometry ----
    // pixBase % 4 == 0 and Wc % 4 == 0 => all 4 pixels share one row.
    const int   h     = pixBase / Wc;
    const int   w0    = pixBase - h * Wc;
    const float ybase = (h + 0.5f) * (1.0f/Hc);

    float4* outM = reinterpret_cast<float4*>(out + MEANS_OFF)  + (size_t)T * 3;
    float4* outS = reinterpret_cast<float4*>(out + SCALES_OFF) + (size_t)T * 3;
    float4* outH = reinterpret_cast<float4*>(out + HARM_OFF)   + (size_t)T * 3;
    float4* outR = reinterpret_cast<float4*>(out + ROT_OFF)    + (size_t)T * 4;

    auto PIX = [&](const float4 A, const float4 Bq, const float4 C,
                   const float dep, const int j,
                   float& mx, float& my, float& mz,
                   float& s0, float& s1, float& s2) -> float4 {
        const float x = (w0 + j + 0.5f) * (1.0f/Wc) + A.x * (1.0f/Wc);
        const float y = ybase + A.y * (1.0f/Hc);

        float dc0 = K0*x + K1*y + K2;
        float dc1 = K3*x + K4*y + K5;
        float dc2 = K6*x + K7*y + K8;
        const float inl = rsqrtf(dc0*dc0 + dc1*dc1 + dc2*dc2);
        dc0 *= inl; dc1 *= inl; dc2 *= inl;

        const float dw0 = R0*dc0 + R1*dc1 + R2*dc2;
        const float dw1 = R3*dc0 + R4*dc1 + R5*dc2;
        const float dw2 = R6*dc0 + R7*dc1 + R8*dc2;

        mx = O0 + dw0*dep;  my = O1 + dw1*dep;  mz = O2 + dw2*dep;

        const float sm = dep * mult;
        s0 = (SCALE_MIN_c + (SCALE_MAX_c - SCALE_MIN_c) / (1.0f + __expf(-A.z))) * sm;
        s1 = (SCALE_MIN_c + (SCALE_MAX_c - SCALE_MIN_c) / (1.0f + __expf(-A.w))) * sm;
        s2 = (SCALE_MIN_c + (SCALE_MAX_c - SCALE_MIN_c) / (1.0f + __expf(-Bq.x))) * sm;

        const float rx = Bq.y, ry = Bq.z, rz = Bq.w, rw = C.x;
        const float rn = 1.0f / (sqrtf(rx*rx + ry*ry + rz*rz + rw*rw) + EPS_c);
        const float bwq = rw*rn, bxq = rx*rn, byq = ry*rn, bzq = rz*rn;
        float4 wq;
        wq.x = aw*bwq - ax*bxq - ay*byq - az*bzq;
        wq.y = aw*bxq + ax*bwq + ay*bzq - az*byq;
        wq.z = aw*byq - ax*bzq + ay*bwq + az*bxq;
        wq.w = aw*bzq + ax*byq - ay*bxq + az*bwq;
        return wq;
    };

    // Stagger stores between pixel bodies so only <=8 m/s temps stay live.
    float A0, A1, A2, S0, S1, S2;     // even-pixel temps
    float C0, C1, C2, E0, E1, E2;     // odd-pixel temps

    outR[0] = PIX(v0, v1, v2,  d4.x, 0, A0, A1, A2, S0, S1, S2);
    outR[1] = PIX(v3, v4, v5,  d4.y, 1, C0, C1, C2, E0, E1, E2);
    outM[0] = make_float4(A0, A1, A2, C0);
    outS[0] = make_float4(S0, S1, S2, E0);
    outH[0] = make_float4(v2.y, v2.z, v2.w, v5.y);

    outR[2] = PIX(v6, v7, v8,  d4.z, 2, A0, A1, A2, S0, S1, S2);
    outM[1] = make_float4(C1, C2, A0, A1);
    outS[1] = make_float4(E1, E2, S0, S1);
    outH[1] = make_float4(v5.z, v5.w, v8.y, v8.z);

    outR[3] = PIX(v9, v10, v11, d4.w, 3, C0, C1, C2, E0, E1, E2);
    outM[2] = make_float4(A2, C0, C1, C2);
    outS[2] = make_float4(S2, E0, E1, E2);
    outH[2] = make_float4(v8.w, v11.y, v11.z, v11.w);
}

extern "C" void kernel_launch(void* const* d_in, const int* in_sizes, int n_in,
                              void* d_out, int out_size, void* d_ws, size_t ws_size,
                              hipStream_t stream) {
    const float* ext    = (const float*)d_in[0];
    const float* intr   = (const float*)d_in[1];
    const float* depths = (const float*)d_in[2];
    const float* opac   = (const float*)d_in[3];
    const float* raw    = (const float*)d_in[4];
    float* out = (float*)d_out;

    ga_kernel<<<TOTc / 1024, 256, 0, stream>>>(ext, intr, depths, opac, raw, out);
}

// Round 6
// 171.728 us; speedup vs baseline: 1.2890x; 1.2890x over previous
//
#include <hip/hip_runtime.h>
#include <math.h>

#define Bc 4
#define Vc 4
#define Hc 256
#define Wc 384
#define HWc (Hc*Wc)               // 98304
#define TOTc (Bc*Vc*HWc)          // 1572864
#define SCALE_MIN_c 1e-05f
#define SCALE_MAX_c 30.0f
#define EPS_c 1e-08f

// Output section offsets (in floats)
#define MEANS_OFF  ((size_t)0)
#define SCALES_OFF ((size_t)TOTc*3)
#define ROT_OFF    ((size_t)TOTc*6)
#define HARM_OFF   ((size_t)TOTc*10)
#define OPAC_OFF   ((size_t)TOTc*13)

// 4 pixels/thread, STRIDED ownership (lane owns waveBase+lane+64k):
//   - rot/opac/depth global accesses are wave-dense directly from registers
//   - 20 independent VMEM loads issued up front (14 KB/wave in flight)
//   - means/scales/harm repacked via three SINGLE-USE per-wave LDS buffers
//     (write once in pixel phase -> __syncthreads -> read once, store dense).
// ROUNDS 3/4 BUG (fixed here): PIX got the GLOBAL pixel index; h/w must come
// from the WITHIN-VIEW index (g % HWc). Global indexing for memory unchanged.
__global__ __launch_bounds__(256, 4) void ga_kernel(
    const float* __restrict__ ext,    // (B,V,4,4)
    const float* __restrict__ intr,   // (B,V,3,3)
    const float* __restrict__ depths, // (B,V,H,W)
    const float* __restrict__ opac,   // (B,V,H,W)
    const float* __restrict__ raw,    // (B,V,H,W,12)
    float* __restrict__ out)
{
    __shared__ float sM[4][768];      // 12 KB means   (wave-private rows)
    __shared__ float sS[4][768];      // 12 KB scales
    __shared__ float sH[4][768];      // 12 KB harmonics

    const int tid  = threadIdx.x;
    const int lane = tid & 63;
    const int wv   = tid >> 6;
    const int waveBase = blockIdx.x * 1024 + wv * 256;        // global pixel base
    const int bview    = blockIdx.x / 96;                     // 96 blocks per view
    const int pvBase   = (blockIdx.x - bview * 96) * 1024 + wv * 256; // within-view
    float* sMw = sM[wv];
    float* sSw = sS[wv];
    float* sHw = sH[wv];

    // ---- issue ALL 20 independent loads up front ----
    const float4* r4 = reinterpret_cast<const float4*>(raw) + (size_t)waveBase * 3;
    const int li = 3 * lane;
    const float4 v0 = r4[      li+0], v1 = r4[      li+1], v2 = r4[      li+2];
    const float  d0 = depths[waveBase       + lane];
    const float  p0 = opac  [waveBase       + lane];
    const float4 v3 = r4[192 + li+0], v4 = r4[192 + li+1], v5 = r4[192 + li+2];
    const float  d1 = depths[waveBase +  64 + lane];
    const float  p1 = opac  [waveBase +  64 + lane];
    const float4 v6 = r4[384 + li+0], v7 = r4[384 + li+1], v8 = r4[384 + li+2];
    const float  d2 = depths[waveBase + 128 + lane];
    const float  p2 = opac  [waveBase + 128 + lane];
    const float4 v9 = r4[576 + li+0], v10= r4[576 + li+1], v11= r4[576 + li+2];
    const float  d3 = depths[waveBase + 192 + lane];
    const float  p3 = opac  [waveBase + 192 + lane];

    // ---- per-view constants (uniform s_loads; computed once per thread) ----
    const float* E = ext  + bview * 16;
    const float* I = intr + bview * 9;

    const float R0 = E[0], R1 = E[4], R2 = E[8];
    const float R3 = E[1], R4 = E[5], R5 = E[9];
    const float R6 = E[2], R7 = E[6], R8 = E[10];
    const float t0 = E[3], t1 = E[7], t2 = E[11];
    const float O0 = -(R0*t0 + R1*t1 + R2*t2);
    const float O1 = -(R3*t0 + R4*t1 + R5*t2);
    const float O2 = -(R6*t0 + R7*t1 + R8*t2);

    const float a00 = I[0]*(1.0f/Wc), a01 = I[1]*(1.0f/Wc), a02 = I[2]*(1.0f/Wc);
    const float a10 = I[3]*(1.0f/Hc), a11 = I[4]*(1.0f/Hc), a12 = I[5]*(1.0f/Hc);
    const float a20 = I[6],           a21 = I[7],           a22 = I[8];
    const float det = a00*(a11*a22 - a12*a21)
                    - a01*(a10*a22 - a12*a20)
                    + a02*(a10*a21 - a11*a20);
    const float id = 1.0f / det;
    const float K0 = (a11*a22 - a12*a21)*id;
    const float K1 = (a02*a21 - a01*a22)*id;
    const float K2 = (a01*a12 - a02*a11)*id;
    const float K3 = (a12*a20 - a10*a22)*id;
    const float K4 = (a00*a22 - a02*a20)*id;
    const float K5 = (a02*a10 - a00*a12)*id;
    const float K6 = (a10*a21 - a11*a20)*id;
    const float K7 = (a01*a20 - a00*a21)*id;
    const float K8 = (a00*a11 - a01*a10)*id;

    const float det2 = a00*a11 - a01*a10;
    const float mult = 0.1f * ((a11*(1.0f/Wc) - a01*(1.0f/Hc))
                             + (-a10*(1.0f/Wc) + a00*(1.0f/Hc))) / det2;

    const float qa0 = sqrtf(fmaxf(0.0f, 1.0f + R0 + R4 + R8));
    const float qa1 = sqrtf(fmaxf(0.0f, 1.0f + R0 - R4 - R8));
    const float qa2 = sqrtf(fmaxf(0.0f, 1.0f - R0 + R4 - R8));
    const float qa3 = sqrtf(fmaxf(0.0f, 1.0f - R0 - R4 + R8));
    float bq = qa0;
    float b0 = qa0*qa0, b1 = R7 - R5, b2 = R2 - R6, b3 = R3 - R1;
    {
        const bool s1 = qa1 > bq;
        b0 = s1 ? (R7 - R5)   : b0;
        b1 = s1 ? (qa1*qa1)   : b1;
        b2 = s1 ? (R3 + R1)   : b2;
        b3 = s1 ? (R2 + R6)   : b3;
        bq = s1 ? qa1 : bq;
        const bool s2 = qa2 > bq;
        b0 = s2 ? (R2 - R6)   : b0;
        b1 = s2 ? (R3 + R1)   : b1;
        b2 = s2 ? (qa2*qa2)   : b2;
        b3 = s2 ? (R5 + R7)   : b3;
        bq = s2 ? qa2 : bq;
        const bool s3 = qa3 > bq;
        b0 = s3 ? (R3 - R1)   : b0;
        b1 = s3 ? (R6 + R2)   : b1;
        b2 = s3 ? (R7 + R5)   : b2;
        b3 = s3 ? (qa3*qa3)   : b3;
        bq = s3 ? qa3 : bq;
    }
    const float dd = 1.0f / (2.0f * fmaxf(bq, 0.1f));
    const float q0 = b0*dd, q1 = b1*dd, q2 = b2*dd, q3 = b3*dd;
    const float qn = 1.0f / sqrtf(q0*q0 + q1*q1 + q2*q2 + q3*q3);
    const float aw = q0*qn, ax = q1*qn, ay = q2*qn, az = q3*qn;

    // ---- per-pixel body: rot returned (stored dense from registers);
    //      means/scales/harm written ONCE into this wave's LDS rows.
    //      p is the WITHIN-VIEW pixel index (geometry only). ----
    auto PIX = [&](const float4 A, const float4 Bq, const float4 C,
                   const float dep, const int p, const int sbase) -> float4 {
        const int h = p / Wc;
        const int w = p - h * Wc;
        const float x = (w + 0.5f) * (1.0f/Wc) + A.x * (1.0f/Wc);
        const float y = (h + 0.5f) * (1.0f/Hc) + A.y * (1.0f/Hc);

        float dc0 = K0*x + K1*y + K2;
        float dc1 = K3*x + K4*y + K5;
        float dc2 = K6*x + K7*y + K8;
        const float inl = rsqrtf(dc0*dc0 + dc1*dc1 + dc2*dc2);
        dc0 *= inl; dc1 *= inl; dc2 *= inl;

        const float dw0 = R0*dc0 + R1*dc1 + R2*dc2;
        const float dw1 = R3*dc0 + R4*dc1 + R5*dc2;
        const float dw2 = R6*dc0 + R7*dc1 + R8*dc2;

        sMw[sbase+0] = O0 + dw0*dep;
        sMw[sbase+1] = O1 + dw1*dep;
        sMw[sbase+2] = O2 + dw2*dep;

        const float sm = dep * mult;
        sSw[sbase+0] = (SCALE_MIN_c + (SCALE_MAX_c - SCALE_MIN_c) / (1.0f + __expf(-A.z))) * sm;
        sSw[sbase+1] = (SCALE_MIN_c + (SCALE_MAX_c - SCALE_MIN_c) / (1.0f + __expf(-A.w))) * sm;
        sSw[sbase+2] = (SCALE_MIN_c + (SCALE_MAX_c - SCALE_MIN_c) / (1.0f + __expf(-Bq.x))) * sm;

        sHw[sbase+0] = C.y;   // raw[9:12] passthrough
        sHw[sbase+1] = C.z;
        sHw[sbase+2] = C.w;

        const float rx = Bq.y, ry = Bq.z, rz = Bq.w, rw = C.x;
        const float rn = 1.0f / (sqrtf(rx*rx + ry*ry + rz*rz + rw*rw) + EPS_c);
        const float bwq = rw*rn, bxq = rx*rn, byq = ry*rn, bzq = rz*rn;
        float4 wq;
        wq.x = aw*bwq - ax*bxq - ay*byq - az*bzq;
        wq.y = aw*bxq + ax*bwq + ay*bzq - az*byq;
        wq.z = aw*byq - ax*bzq + ay*bwq + az*bxq;
        wq.w = aw*bzq + ax*byq - ay*bxq + az*bwq;
        return wq;
    };

    float4* outR4 = reinterpret_cast<float4*>(out + ROT_OFF);

    outR4[waveBase       + lane] = PIX(v0, v1, v2,  d0, pvBase       + lane, (      lane)*3);
    out[OPAC_OFF + waveBase       + lane] = p0;
    outR4[waveBase +  64 + lane] = PIX(v3, v4, v5,  d1, pvBase +  64 + lane, ( 64 + lane)*3);
    out[OPAC_OFF + waveBase +  64 + lane] = p1;
    outR4[waveBase + 128 + lane] = PIX(v6, v7, v8,  d2, pvBase + 128 + lane, (128 + lane)*3);
    out[OPAC_OFF + waveBase + 128 + lane] = p2;
    outR4[waveBase + 192 + lane] = PIX(v9, v10,v11, d3, pvBase + 192 + lane, (192 + lane)*3);
    out[OPAC_OFF + waveBase + 192 + lane] = p3;

    // ---- write/BARRIER/read: bulletproof ordering for the repack ----
    __syncthreads();

    {
        const float4* sv = reinterpret_cast<const float4*>(sMw);
        float4* o = reinterpret_cast<float4*>(out + MEANS_OFF + (size_t)waveBase * 3);
        o[lane] = sv[lane];  o[64 + lane] = sv[64 + lane];  o[128 + lane] = sv[128 + lane];
    }
    {
        const float4* sv = reinterpret_cast<const float4*>(sSw);
        float4* o = reinterpret_cast<float4*>(out + SCALES_OFF + (size_t)waveBase * 3);
        o[lane] = sv[lane];  o[64 + lane] = sv[64 + lane];  o[128 + lane] = sv[128 + lane];
    }
    {
        const float4* sv = reinterpret_cast<const float4*>(sHw);
        float4* o = reinterpret_cast<float4*>(out + HARM_OFF + (size_t)waveBase * 3);
        o[lane] = sv[lane];  o[64 + lane] = sv[64 + lane];  o[128 + lane] = sv[128 + lane];
    }
}

extern "C" void kernel_launch(void* const* d_in, const int* in_sizes, int n_in,
                              void* d_out, int out_size, void* d_ws, size_t ws_size,
                              hipStream_t stream) {
    const float* ext    = (const float*)d_in[0];
    const float* intr   = (const float*)d_in[1];
    const float* depths = (const float*)d_in[2];
    const float* opac   = (const float*)d_in[3];
    const float* raw    = (const float*)d_in[4];
    float* out = (float*)d_out;

    ga_kernel<<<TOTc / 1024, 256, 0, stream>>>(ext, intr, depths, opac, raw, out);
}